// Round 1
// baseline (1773.829 us; speedup 1.0000x reference)
//
#include <hip/hip_runtime.h>
#include <cfloat>

#define BB 4
#define LL 2048
#define DMODEL 256
#define DINNER 512
#define DSTATE 16
#define DTRANK 16
#define HID 128
#define NCLS 4

// ---------------- conv1: x (B,L,9) -> f1 (B,L,128), relu ----------------
__global__ __launch_bounds__(256) void k1_conv1(const float* __restrict__ x,
    const float* __restrict__ w, const float* __restrict__ bias,
    float* __restrict__ f1) {
  int idx = blockIdx.x * 256 + threadIdx.x;  // (b,t,i), i fastest
  int i = idx & 127;
  int t = (idx >> 7) & (LL - 1);
  int b = idx >> 18;
  float acc = bias[i];
#pragma unroll
  for (int k = 0; k < 3; ++k) {
    int tt = t + k - 1;
    if (tt < 0 || tt >= LL) continue;
    const float* xr = x + (b * LL + tt) * 9;
    const float* wr = w + i * 27 + k;
#pragma unroll
    for (int c = 0; c < 9; ++c) acc += xr[c] * wr[c * 3];
  }
  f1[idx] = fmaxf(acc, 0.f);
}

// ---------------- conv2: f1 (B,L,128) -> feat (B,L,256), relu ----------------
// block = one (b, 16-t chunk), 256 threads = output channel o, acc[16] over t
__global__ __launch_bounds__(256) void k2_conv2(const float* __restrict__ f1,
    const float* __restrict__ w, const float* __restrict__ bias,
    float* __restrict__ feat) {
  __shared__ float f1s[18][128];
  int blk = blockIdx.x;
  int b = blk >> 7;            // 128 chunks per b
  int t0 = (blk & 127) * 16;
  int o = threadIdx.x;
  // stage rows t0-1 .. t0+16
  for (int i = threadIdx.x; i < 18 * 128; i += 256) {
    int c = i & 127;
    int r = i >> 7;
    int tt = t0 - 1 + r;
    f1s[r][c] = (tt >= 0 && tt < LL) ? f1[(b * LL + tt) * 128 + c] : 0.f;
  }
  __syncthreads();
  float acc[16];
#pragma unroll
  for (int tt = 0; tt < 16; ++tt) acc[tt] = bias[o];
  const float* wr = w + o * 384;
  for (int i = 0; i < 128; ++i) {
    float w0 = wr[i * 3 + 0];
    float w1 = wr[i * 3 + 1];
    float w2 = wr[i * 3 + 2];
#pragma unroll
    for (int tt = 0; tt < 16; ++tt)
      acc[tt] += f1s[tt][i] * w0 + f1s[tt + 1][i] * w1 + f1s[tt + 2][i] * w2;
  }
#pragma unroll
  for (int tt = 0; tt < 16; ++tt)
    feat[(b * LL + t0 + tt) * 256 + o] = fmaxf(acc[tt], 0.f);
}

// ---------------- generic tiled GEMM: C[M,N] = A[M,K] @ W[N,K]^T ----------------
// BM=BN=64, BK=16, 256 threads, 4x4 microtile. M%64==0, N%64==0, K%16==0.
__global__ __launch_bounds__(256) void k_gemm(const float* __restrict__ A,
    const float* __restrict__ W, float* __restrict__ C, int M, int N, int K) {
  __shared__ float As[16][65];
  __shared__ float Ws[16][65];
  int bm = blockIdx.y, bn = blockIdx.x;
  int tid = threadIdx.x;
  int tr = tid >> 4, tc = tid & 15;
  float acc[4][4] = {};
  for (int k0 = 0; k0 < K; k0 += 16) {
    for (int i = tid; i < 64 * 16; i += 256) {
      int r = i >> 4, c = i & 15;
      As[c][r] = A[(bm * 64 + r) * K + k0 + c];
      Ws[c][r] = W[(bn * 64 + r) * K + k0 + c];
    }
    __syncthreads();
#pragma unroll
    for (int kk = 0; kk < 16; ++kk) {
      float a[4], wv[4];
#pragma unroll
      for (int xx = 0; xx < 4; ++xx) a[xx] = As[kk][tr * 4 + xx];
#pragma unroll
      for (int xx = 0; xx < 4; ++xx) wv[xx] = Ws[kk][tc * 4 + xx];
#pragma unroll
      for (int ii = 0; ii < 4; ++ii)
#pragma unroll
        for (int jj = 0; jj < 4; ++jj) acc[ii][jj] += a[ii] * wv[jj];
    }
    __syncthreads();
  }
#pragma unroll
  for (int ii = 0; ii < 4; ++ii)
#pragma unroll
    for (int jj = 0; jj < 4; ++jj)
      C[(bm * 64 + tr * 4 + ii) * N + bn * 64 + tc * 4 + jj] = acc[ii][jj];
}

// ---------------- depthwise causal conv4 + silu: xz -> u (B,L,512) ----------------
__global__ __launch_bounds__(256) void k4_dwconv(const float* __restrict__ xz,
    const float* __restrict__ w, const float* __restrict__ bias,
    float* __restrict__ u) {
  int idx = blockIdx.x * 256 + threadIdx.x;  // (b,t,d)
  int d = idx & 511;
  int t = (idx >> 9) & (LL - 1);
  int b = idx >> 20;
  float acc = bias[d];
#pragma unroll
  for (int k = 0; k < 4; ++k) {
    int tt = t - 3 + k;
    if (tt >= 0) acc += xz[(b * LL + tt) * 1024 + d] * w[d * 4 + k];
  }
  float sig = 1.f / (1.f + __expf(-acc));
  u[idx] = acc * sig;
}

// ---------------- x_proj: u (8192,512) @ x_proj_w(48,512)^T -> xdbl (8192,48) ----------------
__global__ __launch_bounds__(256) void k5_xproj(const float* __restrict__ u,
    const float* __restrict__ w, float* __restrict__ xdbl) {
  int idx = blockIdx.x * 256 + threadIdx.x;
  if (idx >= BB * LL * 48) return;
  int row = idx / 48;
  int j = idx - row * 48;
  const float* ur = u + row * 512;
  const float* wr = w + j * 512;
  float acc = 0.f;
  for (int k = 0; k < 512; ++k) acc += ur[k] * wr[k];
  xdbl[idx] = acc;
}

// ---------------- dt: softplus(dt_lr @ dt_proj_w^T + b) -> (8192,512) ----------------
__global__ __launch_bounds__(256) void k6_dt(const float* __restrict__ xdbl,
    const float* __restrict__ w, const float* __restrict__ bias,
    float* __restrict__ dt) {
  int idx = blockIdx.x * 256 + threadIdx.x;  // (row, d)
  int d = idx & 511;
  int row = idx >> 9;
  const float* lr = xdbl + row * 48;
  const float* wr = w + d * 16;
  float acc = bias[d];
#pragma unroll
  for (int r = 0; r < 16; ++r) acc += lr[r] * wr[r];
  dt[idx] = (acc > 20.f) ? acc : log1pf(expf(acc));
}

// ---------------- selective scan, fused D*u and silu(z) gate -> y2 (B,L,512) ----------------
// 1 thread per (b,d); 8 blocks x 256 threads. B/C staged per 64-step chunk in LDS.
__global__ __launch_bounds__(256) void k7_scan(const float* __restrict__ dt,
    const float* __restrict__ u, const float* __restrict__ xdbl,
    const float* __restrict__ xz, const float* __restrict__ A_log,
    const float* __restrict__ D_param, float* __restrict__ y2) {
  __shared__ float BC[64][32];
  int b = blockIdx.x >> 1;
  int d = ((blockIdx.x & 1) << 8) + threadIdx.x;
  float A_r[16];
#pragma unroll
  for (int s = 0; s < 16; ++s) A_r[s] = -expf(A_log[d * 16 + s]);
  float Dv = D_param[d];
  float h[16];
#pragma unroll
  for (int s = 0; s < 16; ++s) h[s] = 0.f;
  for (int t0 = 0; t0 < LL; t0 += 64) {
    __syncthreads();
    for (int i = threadIdx.x; i < 64 * 32; i += 256) {
      int tt = i >> 5, j = i & 31;
      BC[tt][j] = xdbl[(b * LL + t0 + tt) * 48 + 16 + j];
    }
    __syncthreads();
    for (int tt = 0; tt < 64; ++tt) {
      int row = b * LL + t0 + tt;
      float dtv = dt[row * 512 + d];
      float uv = u[row * 512 + d];
      float xv = dtv * uv;
      float y = 0.f;
#pragma unroll
      for (int s = 0; s < 16; ++s) {
        float dA = __expf(dtv * A_r[s]);
        h[s] = h[s] * dA + xv * BC[tt][s];
        y += h[s] * BC[tt][16 + s];
      }
      float zv = xz[row * 1024 + 512 + d];
      float sig = 1.f / (1.f + __expf(-zv));
      y2[row * 512 + d] = (y + Dv * uv) * (zv * sig);
    }
  }
}

// ---------------- partial max over t-chunks: mo (B,L,256) -> part (B*32,256) ----------------
__global__ __launch_bounds__(256) void k9_pmax(const float* __restrict__ mo,
    float* __restrict__ part) {
  int blk = blockIdx.x;  // b*32 + chunk
  int b = blk >> 5;
  int ch = blk & 31;
  int o = threadIdx.x;
  float m = -FLT_MAX;
  for (int tt = 0; tt < 64; ++tt)
    m = fmaxf(m, mo[(b * LL + ch * 64 + tt) * 256 + o]);
  part[blk * 256 + o] = m;
}

// ---------------- final: max-reduce + fc1 relu + fc2 -> out (4,4) ----------------
__global__ __launch_bounds__(256) void k10_head(const float* __restrict__ part,
    const float* __restrict__ fc1_w, const float* __restrict__ fc1_b,
    const float* __restrict__ fc2_w, const float* __restrict__ fc2_b,
    float* __restrict__ out) {
  __shared__ float pooled[4][256];
  __shared__ float hbuf[4][128];
  int tid = threadIdx.x;
  for (int idx = tid; idx < 1024; idx += 256) {
    int b = idx >> 8, o = idx & 255;
    float m = -FLT_MAX;
    for (int c = 0; c < 32; ++c) m = fmaxf(m, part[(b * 32 + c) * 256 + o]);
    pooled[b][o] = m;
  }
  __syncthreads();
  for (int idx = tid; idx < 512; idx += 256) {
    int b = idx >> 7, i = idx & 127;
    float acc = fc1_b[i];
    for (int o = 0; o < 256; ++o) acc += pooled[b][o] * fc1_w[i * 256 + o];
    hbuf[b][i] = fmaxf(acc, 0.f);
  }
  __syncthreads();
  if (tid < 16) {
    int b = tid >> 2, c = tid & 3;
    float acc = fc2_b[c];
    for (int i = 0; i < 128; ++i) acc += hbuf[b][i] * fc2_w[c * 128 + i];
    out[b * 4 + c] = acc;
  }
}

extern "C" void kernel_launch(void* const* d_in, const int* in_sizes, int n_in,
                              void* d_out, int out_size, void* d_ws, size_t ws_size,
                              hipStream_t stream) {
  (void)in_sizes; (void)n_in; (void)out_size; (void)ws_size;
  const float* x        = (const float*)d_in[0];
  const float* conv1_w  = (const float*)d_in[1];
  const float* conv1_b  = (const float*)d_in[2];
  const float* conv2_w  = (const float*)d_in[3];
  const float* conv2_b  = (const float*)d_in[4];
  const float* in_proj_w= (const float*)d_in[5];
  const float* dw_w     = (const float*)d_in[6];
  const float* dw_b     = (const float*)d_in[7];
  const float* x_proj_w = (const float*)d_in[8];
  const float* dt_proj_w= (const float*)d_in[9];
  const float* dt_proj_b= (const float*)d_in[10];
  const float* A_log    = (const float*)d_in[11];
  const float* D_param  = (const float*)d_in[12];
  const float* out_proj_w=(const float*)d_in[13];
  const float* fc1_w    = (const float*)d_in[14];
  const float* fc1_b    = (const float*)d_in[15];
  const float* fc2_w    = (const float*)d_in[16];
  const float* fc2_b    = (const float*)d_in[17];
  float* out = (float*)d_out;

  float* ws = (float*)d_ws;
  float* f1   = ws;                    // 4*2048*128  = 1048576
  float* feat = f1 + 1048576;          // 4*2048*256  = 2097152
  float* xz   = feat + 2097152;        // 4*2048*1024 = 8388608
  float* u    = xz + 8388608;          // 4*2048*512  = 4194304
  float* xdbl = u + 4194304;           // 4*2048*48   = 393216
  float* dt   = xdbl + 393216;         // 4194304
  float* y2   = dt + 4194304;          // 4194304
  float* mo   = y2 + 4194304;          // 2097152
  float* part = mo + 2097152;          // 32768

  // conv1
  k1_conv1<<<dim3(BB * LL * 128 / 256), dim3(256), 0, stream>>>(x, conv1_w, conv1_b, f1);
  // conv2
  k2_conv2<<<dim3(BB * 128), dim3(256), 0, stream>>>(f1, conv2_w, conv2_b, feat);
  // in_proj: (8192,256) @ (1024,256)^T -> xz (8192,1024)
  k_gemm<<<dim3(1024 / 64, 8192 / 64), dim3(256), 0, stream>>>(feat, in_proj_w, xz, 8192, 1024, 256);
  // depthwise conv + silu
  k4_dwconv<<<dim3(BB * LL * 512 / 256), dim3(256), 0, stream>>>(xz, dw_w, dw_b, u);
  // x_proj
  k5_xproj<<<dim3((BB * LL * 48 + 255) / 256), dim3(256), 0, stream>>>(u, x_proj_w, xdbl);
  // dt
  k6_dt<<<dim3(BB * LL * 512 / 256), dim3(256), 0, stream>>>(xdbl, dt_proj_w, dt_proj_b, dt);
  // selective scan + gate
  k7_scan<<<dim3(8), dim3(256), 0, stream>>>(dt, u, xdbl, xz, A_log, D_param, y2);
  // out_proj: (8192,512) @ (256,512)^T -> mo (8192,256)
  k_gemm<<<dim3(256 / 64, 8192 / 64), dim3(256), 0, stream>>>(y2, out_proj_w, mo, 8192, 256, 512);
  // partial max
  k9_pmax<<<dim3(128), dim3(256), 0, stream>>>(mo, part);
  // head
  k10_head<<<dim3(1), dim3(256), 0, stream>>>(part, fc1_w, fc1_b, fc2_w, fc2_b, out);
}

// Round 2
// 492.477 us; speedup vs baseline: 3.6018x; 3.6018x over previous
//
#include <hip/hip_runtime.h>
#include <cfloat>

#define BB 4
#define LL 2048
#define DMODEL 256
#define DINNER 512
#define DSTATE 16
#define DTRANK 16
#define HID 128
#define NCLS 4
#define CH 32
#define NC 64

// ---------------- conv1: x (B,L,9) -> f1 (B,L,128), relu ----------------
__global__ __launch_bounds__(256) void k1_conv1(const float* __restrict__ x,
    const float* __restrict__ w, const float* __restrict__ bias,
    float* __restrict__ f1) {
  int idx = blockIdx.x * 256 + threadIdx.x;  // (b,t,i), i fastest
  int i = idx & 127;
  int t = (idx >> 7) & (LL - 1);
  int b = idx >> 18;
  float acc = bias[i];
#pragma unroll
  for (int k = 0; k < 3; ++k) {
    int tt = t + k - 1;
    if (tt < 0 || tt >= LL) continue;
    const float* xr = x + (b * LL + tt) * 9;
    const float* wr = w + i * 27 + k;
#pragma unroll
    for (int c = 0; c < 9; ++c) acc += xr[c] * wr[c * 3];
  }
  f1[idx] = fmaxf(acc, 0.f);
}

// ---------------- conv2: f1 (B,L,128) -> feat (B,L,256), relu ----------------
__global__ __launch_bounds__(256) void k2_conv2(const float* __restrict__ f1,
    const float* __restrict__ w, const float* __restrict__ bias,
    float* __restrict__ feat) {
  __shared__ float f1s[18][128];
  int blk = blockIdx.x;
  int b = blk >> 7;            // 128 chunks per b
  int t0 = (blk & 127) * 16;
  int o = threadIdx.x;
  for (int i = threadIdx.x; i < 18 * 128; i += 256) {
    int c = i & 127;
    int r = i >> 7;
    int tt = t0 - 1 + r;
    f1s[r][c] = (tt >= 0 && tt < LL) ? f1[(b * LL + tt) * 128 + c] : 0.f;
  }
  __syncthreads();
  float acc[16];
#pragma unroll
  for (int tt = 0; tt < 16; ++tt) acc[tt] = bias[o];
  const float* wr = w + o * 384;
  for (int i = 0; i < 128; ++i) {
    float w0 = wr[i * 3 + 0];
    float w1 = wr[i * 3 + 1];
    float w2 = wr[i * 3 + 2];
#pragma unroll
    for (int tt = 0; tt < 16; ++tt)
      acc[tt] += f1s[tt][i] * w0 + f1s[tt + 1][i] * w1 + f1s[tt + 2][i] * w2;
  }
#pragma unroll
  for (int tt = 0; tt < 16; ++tt)
    feat[(b * LL + t0 + tt) * 256 + o] = fmaxf(acc[tt], 0.f);
}

// ---------------- generic tiled GEMM: C[M,N] = A[M,K] @ W[N,K]^T ----------------
__global__ __launch_bounds__(256) void k_gemm(const float* __restrict__ A,
    const float* __restrict__ W, float* __restrict__ C, int M, int N, int K) {
  __shared__ float As[16][65];
  __shared__ float Ws[16][65];
  int bm = blockIdx.y, bn = blockIdx.x;
  int tid = threadIdx.x;
  int tr = tid >> 4, tc = tid & 15;
  float acc[4][4] = {};
  for (int k0 = 0; k0 < K; k0 += 16) {
    for (int i = tid; i < 64 * 16; i += 256) {
      int r = i >> 4, c = i & 15;
      As[c][r] = A[(bm * 64 + r) * K + k0 + c];
      Ws[c][r] = W[(bn * 64 + r) * K + k0 + c];
    }
    __syncthreads();
#pragma unroll
    for (int kk = 0; kk < 16; ++kk) {
      float a[4], wv[4];
#pragma unroll
      for (int xx = 0; xx < 4; ++xx) a[xx] = As[kk][tr * 4 + xx];
#pragma unroll
      for (int xx = 0; xx < 4; ++xx) wv[xx] = Ws[kk][tc * 4 + xx];
#pragma unroll
      for (int ii = 0; ii < 4; ++ii)
#pragma unroll
        for (int jj = 0; jj < 4; ++jj) acc[ii][jj] += a[ii] * wv[jj];
    }
    __syncthreads();
  }
#pragma unroll
  for (int ii = 0; ii < 4; ++ii)
#pragma unroll
    for (int jj = 0; jj < 4; ++jj)
      C[(bm * 64 + tr * 4 + ii) * N + bn * 64 + tc * 4 + jj] = acc[ii][jj];
}

// ---------------- depthwise causal conv4 + silu: xz -> u (B,L,512) ----------------
__global__ __launch_bounds__(256) void k4_dwconv(const float* __restrict__ xz,
    const float* __restrict__ w, const float* __restrict__ bias,
    float* __restrict__ u) {
  int idx = blockIdx.x * 256 + threadIdx.x;  // (b,t,d)
  int d = idx & 511;
  int t = (idx >> 9) & (LL - 1);
  int b = idx >> 20;
  float acc = bias[d];
#pragma unroll
  for (int k = 0; k < 4; ++k) {
    int tt = t - 3 + k;
    if (tt >= 0) acc += xz[(b * LL + tt) * 1024 + d] * w[d * 4 + k];
  }
  float sig = 1.f / (1.f + __expf(-acc));
  u[idx] = acc * sig;
}

// ---------------- x_proj: u (8192,512) @ x_proj_w(48,512)^T -> xdbl (8192,48) ----------------
__global__ __launch_bounds__(256) void k5_xproj(const float* __restrict__ u,
    const float* __restrict__ w, float* __restrict__ xdbl) {
  int idx = blockIdx.x * 256 + threadIdx.x;
  if (idx >= BB * LL * 48) return;
  int row = idx / 48;
  int j = idx - row * 48;
  const float* ur = u + row * 512;
  const float* wr = w + j * 512;
  float acc = 0.f;
  for (int k = 0; k < 512; ++k) acc += ur[k] * wr[k];
  xdbl[idx] = acc;
}

// ---------------- dt: softplus(dt_lr @ dt_proj_w^T + b) -> (8192,512) ----------------
__global__ __launch_bounds__(256) void k6_dt(const float* __restrict__ xdbl,
    const float* __restrict__ w, const float* __restrict__ bias,
    float* __restrict__ dt) {
  int idx = blockIdx.x * 256 + threadIdx.x;  // (row, d)
  int d = idx & 511;
  int row = idx >> 9;
  const float* lr = xdbl + row * 48;
  const float* wr = w + d * 16;
  float acc = bias[d];
#pragma unroll
  for (int r = 0; r < 16; ++r) acc += lr[r] * wr[r];
  dt[idx] = (acc > 20.f) ? acc : log1pf(expf(acc));
}

// ======== chunked selective scan: 3 passes ========
// pass1: per (b,chunk,d): local scan (h_in=0) -> hloc[b,c,s,d], dtsum[b,c,d]
__global__ __launch_bounds__(512) void k7a_pass1(const float* __restrict__ dt,
    const float* __restrict__ u, const float* __restrict__ xdbl,
    const float* __restrict__ A_log, float* __restrict__ hloc,
    float* __restrict__ dtsum) {
  __shared__ float Bs[CH][16];
  int b = blockIdx.x >> 6;
  int c = blockIdx.x & (NC - 1);
  int d = threadIdx.x;
  {
    int t = threadIdx.x >> 4, s = threadIdx.x & 15;   // 512 = 32*16
    Bs[t][s] = xdbl[(b * LL + c * CH + t) * 48 + 16 + s];
  }
  __syncthreads();
  float A_r[16];
#pragma unroll
  for (int s = 0; s < 16; ++s) A_r[s] = -__expf(A_log[d * 16 + s]);
  float h[16];
#pragma unroll
  for (int s = 0; s < 16; ++s) h[s] = 0.f;
  float dsum = 0.f;
  const float* dtp = dt + (size_t)(b * LL + c * CH) * 512 + d;
  const float* up  = u  + (size_t)(b * LL + c * CH) * 512 + d;
  for (int t = 0; t < CH; ++t) {
    float dtv = dtp[t * 512];
    float uv  = up[t * 512];
    float xv = dtv * uv;
    dsum += dtv;
#pragma unroll
    for (int s = 0; s < 16; ++s)
      h[s] = h[s] * __expf(dtv * A_r[s]) + xv * Bs[t][s];
  }
  int base = b * NC + c;
#pragma unroll
  for (int s = 0; s < 16; ++s) hloc[(base * 16 + s) * 512 + d] = h[s];
  dtsum[base * 512 + d] = dsum;
}

// pass2: per (b,s,d): sequential combine over chunks -> h_in[b,c,s,d]
__global__ __launch_bounds__(512) void k7b_combine(const float* __restrict__ hloc,
    const float* __restrict__ dtsum, const float* __restrict__ A_log,
    float* __restrict__ h_in) {
  int g = blockIdx.x * 512 + threadIdx.x;   // 4*16*512 = 32768 threads
  int d = g & 511;
  int s = (g >> 9) & 15;
  int b = g >> 13;
  float A_r = -__expf(A_log[d * 16 + s]);
  float H = 0.f;
  for (int c = 0; c < NC; ++c) {
    int base = b * NC + c;
    h_in[(base * 16 + s) * 512 + d] = H;
    float P = __expf(A_r * dtsum[base * 512 + d]);
    H = P * H + hloc[(base * 16 + s) * 512 + d];
  }
}

// pass3: per (b,chunk,d): replay with correct h_in, fuse D*u + silu(z) gate -> y2
__global__ __launch_bounds__(512) void k7c_pass3(const float* __restrict__ dt,
    const float* __restrict__ u, const float* __restrict__ xdbl,
    const float* __restrict__ xz, const float* __restrict__ A_log,
    const float* __restrict__ D_param, const float* __restrict__ h_in,
    float* __restrict__ y2) {
  __shared__ float BC[CH][32];
  int b = blockIdx.x >> 6;
  int c = blockIdx.x & (NC - 1);
  int d = threadIdx.x;
  for (int i = threadIdx.x; i < CH * 32; i += 512) {
    int t = i >> 5, j = i & 31;
    BC[t][j] = xdbl[(b * LL + c * CH + t) * 48 + 16 + j];
  }
  __syncthreads();
  float A_r[16];
#pragma unroll
  for (int s = 0; s < 16; ++s) A_r[s] = -__expf(A_log[d * 16 + s]);
  float Dv = D_param[d];
  int base = b * NC + c;
  float h[16];
#pragma unroll
  for (int s = 0; s < 16; ++s) h[s] = h_in[(base * 16 + s) * 512 + d];
  for (int t = 0; t < CH; ++t) {
    int row = b * LL + c * CH + t;
    float dtv = dt[(size_t)row * 512 + d];
    float uv  = u[(size_t)row * 512 + d];
    float xv = dtv * uv;
    float y = 0.f;
#pragma unroll
    for (int s = 0; s < 16; ++s) {
      h[s] = h[s] * __expf(dtv * A_r[s]) + xv * BC[t][s];
      y += h[s] * BC[t][16 + s];
    }
    float zv = xz[(size_t)row * 1024 + 512 + d];
    float sig = 1.f / (1.f + __expf(-zv));
    y2[(size_t)row * 512 + d] = (y + Dv * uv) * (zv * sig);
  }
}

// ---------------- partial max over t-chunks: mo (B,L,256) -> part (B*32,256) ----------------
__global__ __launch_bounds__(256) void k9_pmax(const float* __restrict__ mo,
    float* __restrict__ part) {
  int blk = blockIdx.x;  // b*32 + chunk
  int b = blk >> 5;
  int ch = blk & 31;
  int o = threadIdx.x;
  float m = -FLT_MAX;
  for (int tt = 0; tt < 64; ++tt)
    m = fmaxf(m, mo[(b * LL + ch * 64 + tt) * 256 + o]);
  part[blk * 256 + o] = m;
}

// ---------------- final: max-reduce + fc1 relu + fc2 -> out (4,4) ----------------
__global__ __launch_bounds__(256) void k10_head(const float* __restrict__ part,
    const float* __restrict__ fc1_w, const float* __restrict__ fc1_b,
    const float* __restrict__ fc2_w, const float* __restrict__ fc2_b,
    float* __restrict__ out) {
  __shared__ float pooled[4][256];
  __shared__ float hbuf[4][128];
  int tid = threadIdx.x;
  for (int idx = tid; idx < 1024; idx += 256) {
    int b = idx >> 8, o = idx & 255;
    float m = -FLT_MAX;
    for (int c = 0; c < 32; ++c) m = fmaxf(m, part[(b * 32 + c) * 256 + o]);
    pooled[b][o] = m;
  }
  __syncthreads();
  for (int idx = tid; idx < 512; idx += 256) {
    int b = idx >> 7, i = idx & 127;
    float acc = fc1_b[i];
    for (int o = 0; o < 256; ++o) acc += pooled[b][o] * fc1_w[i * 256 + o];
    hbuf[b][i] = fmaxf(acc, 0.f);
  }
  __syncthreads();
  if (tid < 16) {
    int b = tid >> 2, c = tid & 3;
    float acc = fc2_b[c];
    for (int i = 0; i < 128; ++i) acc += hbuf[b][i] * fc2_w[c * 128 + i];
    out[b * 4 + c] = acc;
  }
}

extern "C" void kernel_launch(void* const* d_in, const int* in_sizes, int n_in,
                              void* d_out, int out_size, void* d_ws, size_t ws_size,
                              hipStream_t stream) {
  (void)in_sizes; (void)n_in; (void)out_size; (void)ws_size;
  const float* x        = (const float*)d_in[0];
  const float* conv1_w  = (const float*)d_in[1];
  const float* conv1_b  = (const float*)d_in[2];
  const float* conv2_w  = (const float*)d_in[3];
  const float* conv2_b  = (const float*)d_in[4];
  const float* in_proj_w= (const float*)d_in[5];
  const float* dw_w     = (const float*)d_in[6];
  const float* dw_b     = (const float*)d_in[7];
  const float* x_proj_w = (const float*)d_in[8];
  const float* dt_proj_w= (const float*)d_in[9];
  const float* dt_proj_b= (const float*)d_in[10];
  const float* A_log    = (const float*)d_in[11];
  const float* D_param  = (const float*)d_in[12];
  const float* out_proj_w=(const float*)d_in[13];
  const float* fc1_w    = (const float*)d_in[14];
  const float* fc1_b    = (const float*)d_in[15];
  const float* fc2_w    = (const float*)d_in[16];
  const float* fc2_b    = (const float*)d_in[17];
  float* out = (float*)d_out;

  float* ws = (float*)d_ws;
  float* f1   = ws;                    // 4*2048*128  = 1048576
  float* feat = f1 + 1048576;          // 4*2048*256  = 2097152
  float* xz   = feat + 2097152;        // 4*2048*1024 = 8388608
  float* u    = xz + 8388608;          // 4*2048*512  = 4194304
  float* xdbl = u + 4194304;           // 4*2048*48   = 393216
  float* dt   = xdbl + 393216;         // 4194304
  float* y2   = dt + 4194304;          // 4194304
  float* mo   = y2 + 4194304;          // 2097152
  float* part = mo + 2097152;          // 32768

  // scan scratch ALIASES dead regions (all consumed before out_proj writes mo):
  float* hloc  = mo;    // 4*64*16*512 = 2097152 floats, mo is free until out_proj
  float* h_in  = feat;  // feat dead after in_proj GEMM
  float* dtsum = f1;    // f1 dead after conv2

  k1_conv1<<<dim3(BB * LL * 128 / 256), dim3(256), 0, stream>>>(x, conv1_w, conv1_b, f1);
  k2_conv2<<<dim3(BB * 128), dim3(256), 0, stream>>>(f1, conv2_w, conv2_b, feat);
  k_gemm<<<dim3(1024 / 64, 8192 / 64), dim3(256), 0, stream>>>(feat, in_proj_w, xz, 8192, 1024, 256);
  k4_dwconv<<<dim3(BB * LL * 512 / 256), dim3(256), 0, stream>>>(xz, dw_w, dw_b, u);
  k5_xproj<<<dim3((BB * LL * 48 + 255) / 256), dim3(256), 0, stream>>>(u, x_proj_w, xdbl);
  k6_dt<<<dim3(BB * LL * 512 / 256), dim3(256), 0, stream>>>(xdbl, dt_proj_w, dt_proj_b, dt);
  // chunked scan
  k7a_pass1<<<dim3(BB * NC), dim3(512), 0, stream>>>(dt, u, xdbl, A_log, hloc, dtsum);
  k7b_combine<<<dim3(BB * 16), dim3(512), 0, stream>>>(hloc, dtsum, A_log, h_in);
  k7c_pass3<<<dim3(BB * NC), dim3(512), 0, stream>>>(dt, u, xdbl, xz, A_log, D_param, h_in, y2);
  // out_proj
  k_gemm<<<dim3(256 / 64, 8192 / 64), dim3(256), 0, stream>>>(y2, out_proj_w, mo, 8192, 256, 512);
  k9_pmax<<<dim3(128), dim3(256), 0, stream>>>(mo, part);
  k10_head<<<dim3(1), dim3(256), 0, stream>>>(part, fc1_w, fc1_b, fc2_w, fc2_b, out);
}

// Round 3
// 418.744 us; speedup vs baseline: 4.2361x; 1.1761x over previous
//
#include <hip/hip_runtime.h>
#include <cfloat>

#define BB 4
#define LL 2048
#define DMODEL 256
#define DINNER 512
#define DSTATE 16
#define DTRANK 16
#define HID 128
#define NCLS 4
#define CH 32
#define NC 64

// ---------------- conv1: x (B,L,9) -> f1 (B,L,128), relu ----------------
__global__ __launch_bounds__(256) void k1_conv1(const float* __restrict__ x,
    const float* __restrict__ w, const float* __restrict__ bias,
    float* __restrict__ f1) {
  int idx = blockIdx.x * 256 + threadIdx.x;  // (b,t,i), i fastest
  int i = idx & 127;
  int t = (idx >> 7) & (LL - 1);
  int b = idx >> 18;
  float acc = bias[i];
#pragma unroll
  for (int k = 0; k < 3; ++k) {
    int tt = t + k - 1;
    if (tt < 0 || tt >= LL) continue;
    const float* xr = x + (b * LL + tt) * 9;
    const float* wr = w + i * 27 + k;
#pragma unroll
    for (int c = 0; c < 9; ++c) acc += xr[c] * wr[c * 3];
  }
  f1[idx] = fmaxf(acc, 0.f);
}

// ---------------- conv2: f1 (B,L,128) -> feat (B,L,256), relu ----------------
__global__ __launch_bounds__(256) void k2_conv2(const float* __restrict__ f1,
    const float* __restrict__ w, const float* __restrict__ bias,
    float* __restrict__ feat) {
  __shared__ float f1s[18][128];
  int blk = blockIdx.x;
  int b = blk >> 7;            // 128 chunks per b
  int t0 = (blk & 127) * 16;
  int o = threadIdx.x;
  for (int i = threadIdx.x; i < 18 * 128; i += 256) {
    int c = i & 127;
    int r = i >> 7;
    int tt = t0 - 1 + r;
    f1s[r][c] = (tt >= 0 && tt < LL) ? f1[(b * LL + tt) * 128 + c] : 0.f;
  }
  __syncthreads();
  float acc[16];
#pragma unroll
  for (int tt = 0; tt < 16; ++tt) acc[tt] = bias[o];
  const float* wr = w + o * 384;
  for (int i = 0; i < 128; ++i) {
    float w0 = wr[i * 3 + 0];
    float w1 = wr[i * 3 + 1];
    float w2 = wr[i * 3 + 2];
#pragma unroll
    for (int tt = 0; tt < 16; ++tt)
      acc[tt] += f1s[tt][i] * w0 + f1s[tt + 1][i] * w1 + f1s[tt + 2][i] * w2;
  }
#pragma unroll
  for (int tt = 0; tt < 16; ++tt)
    feat[(b * LL + t0 + tt) * 256 + o] = fmaxf(acc[tt], 0.f);
}

// ---------------- generic tiled GEMM: C[M,N] = A[M,K] @ W[N,K]^T ----------------
__global__ __launch_bounds__(256) void k_gemm(const float* __restrict__ A,
    const float* __restrict__ W, float* __restrict__ C, int M, int N, int K) {
  __shared__ float As[16][65];
  __shared__ float Ws[16][65];
  int bm = blockIdx.y, bn = blockIdx.x;
  int tid = threadIdx.x;
  int tr = tid >> 4, tc = tid & 15;
  float acc[4][4] = {};
  for (int k0 = 0; k0 < K; k0 += 16) {
    for (int i = tid; i < 64 * 16; i += 256) {
      int r = i >> 4, c = i & 15;
      As[c][r] = A[(bm * 64 + r) * K + k0 + c];
      Ws[c][r] = W[(bn * 64 + r) * K + k0 + c];
    }
    __syncthreads();
#pragma unroll
    for (int kk = 0; kk < 16; ++kk) {
      float a[4], wv[4];
#pragma unroll
      for (int xx = 0; xx < 4; ++xx) a[xx] = As[kk][tr * 4 + xx];
#pragma unroll
      for (int xx = 0; xx < 4; ++xx) wv[xx] = Ws[kk][tc * 4 + xx];
#pragma unroll
      for (int ii = 0; ii < 4; ++ii)
#pragma unroll
        for (int jj = 0; jj < 4; ++jj) acc[ii][jj] += a[ii] * wv[jj];
    }
    __syncthreads();
  }
#pragma unroll
  for (int ii = 0; ii < 4; ++ii)
#pragma unroll
    for (int jj = 0; jj < 4; ++jj)
      C[(bm * 64 + tr * 4 + ii) * N + bn * 64 + tc * 4 + jj] = acc[ii][jj];
}

// ---------------- depthwise causal conv4 + silu: xz -> u (B,L,512) ----------------
__global__ __launch_bounds__(256) void k4_dwconv(const float* __restrict__ xz,
    const float* __restrict__ w, const float* __restrict__ bias,
    float* __restrict__ u) {
  int idx = blockIdx.x * 256 + threadIdx.x;  // (b,t,d)
  int d = idx & 511;
  int t = (idx >> 9) & (LL - 1);
  int b = idx >> 20;
  float acc = bias[d];
#pragma unroll
  for (int k = 0; k < 4; ++k) {
    int tt = t - 3 + k;
    if (tt >= 0) acc += xz[(b * LL + tt) * 1024 + d] * w[d * 4 + k];
  }
  float sig = 1.f / (1.f + __expf(-acc));
  u[idx] = acc * sig;
}

// ---------------- x_proj (LDS-staged): u (8192,512) @ w(48,512)^T -> xdbl (8192,48) ----
// 32 rows/block, 48 cols, K in 4 chunks of 128. A-tile + W-tile staged in LDS.
__global__ __launch_bounds__(256) void k5_xproj(const float* __restrict__ u,
    const float* __restrict__ w, float* __restrict__ xdbl) {
  __shared__ float As[32][129];
  __shared__ float Ws[48][129];
  int r0 = blockIdx.x * 32;    // 256 blocks
  int tid = threadIdx.x;
  int r = tid >> 3;            // 0..31: row within tile
  int jg = tid & 7;            // 0..7: 6 output cols each
  float acc[6] = {};
  for (int k0 = 0; k0 < 512; k0 += 128) {
    __syncthreads();
    // stage A: 32 rows x 128 cols = 1024 float4
    for (int i = tid; i < 32 * 32; i += 256) {
      int rr = i >> 5;
      int cc = (i & 31) << 2;
      float4 v = *(const float4*)(u + (size_t)(r0 + rr) * 512 + k0 + cc);
      As[rr][cc] = v.x; As[rr][cc + 1] = v.y; As[rr][cc + 2] = v.z; As[rr][cc + 3] = v.w;
    }
    // stage W: 48 rows x 128 cols = 1536 float4
    for (int i = tid; i < 48 * 32; i += 256) {
      int jj = i >> 5;
      int cc = (i & 31) << 2;
      float4 v = *(const float4*)(w + (size_t)jj * 512 + k0 + cc);
      Ws[jj][cc] = v.x; Ws[jj][cc + 1] = v.y; Ws[jj][cc + 2] = v.z; Ws[jj][cc + 3] = v.w;
    }
    __syncthreads();
    for (int k = 0; k < 128; ++k) {
      float a = As[r][k];
#pragma unroll
      for (int jj = 0; jj < 6; ++jj)
        acc[jj] += a * Ws[jg * 6 + jj][k];
    }
  }
  int row = r0 + r;
#pragma unroll
  for (int jj = 0; jj < 6; ++jj)
    xdbl[(size_t)row * 48 + jg * 6 + jj] = acc[jj];
}

// ---------------- dt: softplus(dt_lr @ dt_proj_w^T + b) -> (8192,512) ----------------
__global__ __launch_bounds__(256) void k6_dt(const float* __restrict__ xdbl,
    const float* __restrict__ w, const float* __restrict__ bias,
    float* __restrict__ dt) {
  int idx = blockIdx.x * 256 + threadIdx.x;  // (row, d)
  int d = idx & 511;
  int row = idx >> 9;
  const float* lr = xdbl + row * 48;
  const float* wr = w + d * 16;
  float acc = bias[d];
#pragma unroll
  for (int r = 0; r < 16; ++r) acc += lr[r] * wr[r];
  dt[idx] = (acc > 20.f) ? acc : log1pf(expf(acc));
}

// ======== chunked selective scan: 3 passes ========
__global__ __launch_bounds__(512) void k7a_pass1(const float* __restrict__ dt,
    const float* __restrict__ u, const float* __restrict__ xdbl,
    const float* __restrict__ A_log, float* __restrict__ hloc,
    float* __restrict__ dtsum) {
  __shared__ float Bs[CH][16];
  int b = blockIdx.x >> 6;
  int c = blockIdx.x & (NC - 1);
  int d = threadIdx.x;
  {
    int t = threadIdx.x >> 4, s = threadIdx.x & 15;
    Bs[t][s] = xdbl[(b * LL + c * CH + t) * 48 + 16 + s];
  }
  __syncthreads();
  float A_r[16];
#pragma unroll
  for (int s = 0; s < 16; ++s) A_r[s] = -__expf(A_log[d * 16 + s]);
  float h[16];
#pragma unroll
  for (int s = 0; s < 16; ++s) h[s] = 0.f;
  float dsum = 0.f;
  const float* dtp = dt + (size_t)(b * LL + c * CH) * 512 + d;
  const float* up  = u  + (size_t)(b * LL + c * CH) * 512 + d;
  for (int t = 0; t < CH; ++t) {
    float dtv = dtp[t * 512];
    float uv  = up[t * 512];
    float xv = dtv * uv;
    dsum += dtv;
#pragma unroll
    for (int s = 0; s < 16; ++s)
      h[s] = h[s] * __expf(dtv * A_r[s]) + xv * Bs[t][s];
  }
  int base = b * NC + c;
#pragma unroll
  for (int s = 0; s < 16; ++s) hloc[(base * 16 + s) * 512 + d] = h[s];
  dtsum[base * 512 + d] = dsum;
}

__global__ __launch_bounds__(512) void k7b_combine(const float* __restrict__ hloc,
    const float* __restrict__ dtsum, const float* __restrict__ A_log,
    float* __restrict__ h_in) {
  int g = blockIdx.x * 512 + threadIdx.x;
  int d = g & 511;
  int s = (g >> 9) & 15;
  int b = g >> 13;
  float A_r = -__expf(A_log[d * 16 + s]);
  float H = 0.f;
  for (int c = 0; c < NC; ++c) {
    int base = b * NC + c;
    h_in[(base * 16 + s) * 512 + d] = H;
    float P = __expf(A_r * dtsum[base * 512 + d]);
    H = P * H + hloc[(base * 16 + s) * 512 + d];
  }
}

__global__ __launch_bounds__(512) void k7c_pass3(const float* __restrict__ dt,
    const float* __restrict__ u, const float* __restrict__ xdbl,
    const float* __restrict__ xz, const float* __restrict__ A_log,
    const float* __restrict__ D_param, const float* __restrict__ h_in,
    float* __restrict__ y2) {
  __shared__ float BC[CH][32];
  int b = blockIdx.x >> 6;
  int c = blockIdx.x & (NC - 1);
  int d = threadIdx.x;
  for (int i = threadIdx.x; i < CH * 32; i += 512) {
    int t = i >> 5, j = i & 31;
    BC[t][j] = xdbl[(b * LL + c * CH + t) * 48 + 16 + j];
  }
  __syncthreads();
  float A_r[16];
#pragma unroll
  for (int s = 0; s < 16; ++s) A_r[s] = -__expf(A_log[d * 16 + s]);
  float Dv = D_param[d];
  int base = b * NC + c;
  float h[16];
#pragma unroll
  for (int s = 0; s < 16; ++s) h[s] = h_in[(base * 16 + s) * 512 + d];
  for (int t = 0; t < CH; ++t) {
    int row = b * LL + c * CH + t;
    float dtv = dt[(size_t)row * 512 + d];
    float uv  = u[(size_t)row * 512 + d];
    float xv = dtv * uv;
    float y = 0.f;
#pragma unroll
    for (int s = 0; s < 16; ++s) {
      h[s] = h[s] * __expf(dtv * A_r[s]) + xv * BC[t][s];
      y += h[s] * BC[t][16 + s];
    }
    float zv = xz[(size_t)row * 1024 + 512 + d];
    float sig = 1.f / (1.f + __expf(-zv));
    y2[(size_t)row * 512 + d] = (y + Dv * uv) * (zv * sig);
  }
}

// ---------------- partial max over t-chunks: mo (B,L,256) -> part (B*32,256) ----------------
__global__ __launch_bounds__(256) void k9_pmax(const float* __restrict__ mo,
    float* __restrict__ part) {
  int blk = blockIdx.x;
  int b = blk >> 5;
  int ch = blk & 31;
  int o = threadIdx.x;
  float m = -FLT_MAX;
  for (int tt = 0; tt < 64; ++tt)
    m = fmaxf(m, mo[(b * LL + ch * 64 + tt) * 256 + o]);
  part[blk * 256 + o] = m;
}

// ---------------- final: max-reduce + fc1 relu + fc2 -> out (4,4) ----------------
__global__ __launch_bounds__(256) void k10_head(const float* __restrict__ part,
    const float* __restrict__ fc1_w, const float* __restrict__ fc1_b,
    const float* __restrict__ fc2_w, const float* __restrict__ fc2_b,
    float* __restrict__ out) {
  __shared__ float pooled[4][256];
  __shared__ float hbuf[4][128];
  int tid = threadIdx.x;
  for (int idx = tid; idx < 1024; idx += 256) {
    int b = idx >> 8, o = idx & 255;
    float m = -FLT_MAX;
    for (int c = 0; c < 32; ++c) m = fmaxf(m, part[(b * 32 + c) * 256 + o]);
    pooled[b][o] = m;
  }
  __syncthreads();
  for (int idx = tid; idx < 512; idx += 256) {
    int b = idx >> 7, i = idx & 127;
    float acc = fc1_b[i];
    for (int o = 0; o < 256; ++o) acc += pooled[b][o] * fc1_w[i * 256 + o];
    hbuf[b][i] = fmaxf(acc, 0.f);
  }
  __syncthreads();
  if (tid < 16) {
    int b = tid >> 2, c = tid & 3;
    float acc = fc2_b[c];
    for (int i = 0; i < 128; ++i) acc += hbuf[b][i] * fc2_w[c * 128 + i];
    out[b * 4 + c] = acc;
  }
}

extern "C" void kernel_launch(void* const* d_in, const int* in_sizes, int n_in,
                              void* d_out, int out_size, void* d_ws, size_t ws_size,
                              hipStream_t stream) {
  (void)in_sizes; (void)n_in; (void)out_size; (void)ws_size;
  const float* x        = (const float*)d_in[0];
  const float* conv1_w  = (const float*)d_in[1];
  const float* conv1_b  = (const float*)d_in[2];
  const float* conv2_w  = (const float*)d_in[3];
  const float* conv2_b  = (const float*)d_in[4];
  const float* in_proj_w= (const float*)d_in[5];
  const float* dw_w     = (const float*)d_in[6];
  const float* dw_b     = (const float*)d_in[7];
  const float* x_proj_w = (const float*)d_in[8];
  const float* dt_proj_w= (const float*)d_in[9];
  const float* dt_proj_b= (const float*)d_in[10];
  const float* A_log    = (const float*)d_in[11];
  const float* D_param  = (const float*)d_in[12];
  const float* out_proj_w=(const float*)d_in[13];
  const float* fc1_w    = (const float*)d_in[14];
  const float* fc1_b    = (const float*)d_in[15];
  const float* fc2_w    = (const float*)d_in[16];
  const float* fc2_b    = (const float*)d_in[17];
  float* out = (float*)d_out;

  float* ws = (float*)d_ws;
  float* f1   = ws;                    // 4*2048*128  = 1048576
  float* feat = f1 + 1048576;          // 4*2048*256  = 2097152
  float* xz   = feat + 2097152;        // 4*2048*1024 = 8388608
  float* u    = xz + 8388608;          // 4*2048*512  = 4194304
  float* xdbl = u + 4194304;           // 4*2048*48   = 393216
  float* dt   = xdbl + 393216;         // 4194304
  float* y2   = dt + 4194304;          // 4194304
  float* mo   = y2 + 4194304;          // 2097152
  float* part = mo + 2097152;          // 32768

  float* hloc  = mo;    // aliases: free until out_proj
  float* h_in  = feat;  // dead after in_proj GEMM
  float* dtsum = f1;    // dead after conv2

  k1_conv1<<<dim3(BB * LL * 128 / 256), dim3(256), 0, stream>>>(x, conv1_w, conv1_b, f1);
  k2_conv2<<<dim3(BB * 128), dim3(256), 0, stream>>>(f1, conv2_w, conv2_b, feat);
  k_gemm<<<dim3(1024 / 64, 8192 / 64), dim3(256), 0, stream>>>(feat, in_proj_w, xz, 8192, 1024, 256);
  k4_dwconv<<<dim3(BB * LL * 512 / 256), dim3(256), 0, stream>>>(xz, dw_w, dw_b, u);
  k5_xproj<<<dim3(256), dim3(256), 0, stream>>>(u, x_proj_w, xdbl);
  k6_dt<<<dim3(BB * LL * 512 / 256), dim3(256), 0, stream>>>(xdbl, dt_proj_w, dt_proj_b, dt);
  k7a_pass1<<<dim3(BB * NC), dim3(512), 0, stream>>>(dt, u, xdbl, A_log, hloc, dtsum);
  k7b_combine<<<dim3(BB * 16), dim3(512), 0, stream>>>(hloc, dtsum, A_log, h_in);
  k7c_pass3<<<dim3(BB * NC), dim3(512), 0, stream>>>(dt, u, xdbl, xz, A_log, D_param, h_in, y2);
  k_gemm<<<dim3(256 / 64, 8192 / 64), dim3(256), 0, stream>>>(y2, out_proj_w, mo, 8192, 256, 512);
  k9_pmax<<<dim3(128), dim3(256), 0, stream>>>(mo, part);
  k10_head<<<dim3(1), dim3(256), 0, stream>>>(part, fc1_w, fc1_b, fc2_w, fc2_b, out);
}

// Round 4
// 334.490 us; speedup vs baseline: 5.3031x; 1.2519x over previous
//
#include <hip/hip_runtime.h>
#include <cfloat>

#define BB 4
#define LL 2048
#define DMODEL 256
#define DINNER 512
#define DSTATE 16
#define DTRANK 16
#define HID 128
#define NCLS 4
#define CH 32
#define NC 64

typedef unsigned short u16;
typedef __attribute__((ext_vector_type(8))) short bf16x8;
typedef __attribute__((ext_vector_type(4))) float f32x4;

// float -> bf16 (RNE) and back
__device__ inline u16 f2b(float v) {
  union { float f; unsigned u; } c; c.f = v;
  unsigned r = c.u + 0x7fffu + ((c.u >> 16) & 1u);
  return (u16)(r >> 16);
}
__device__ inline float b2f(u16 h) {
  union { unsigned u; float f; } c; c.u = ((unsigned)h) << 16;
  return c.f;
}

// ---------------- conv1: x (B,L,9) -> f1 (B,L,128), relu ----------------
__global__ __launch_bounds__(256) void k1_conv1(const float* __restrict__ x,
    const float* __restrict__ w, const float* __restrict__ bias,
    float* __restrict__ f1) {
  int idx = blockIdx.x * 256 + threadIdx.x;
  int i = idx & 127;
  int t = (idx >> 7) & (LL - 1);
  int b = idx >> 18;
  float acc = bias[i];
#pragma unroll
  for (int k = 0; k < 3; ++k) {
    int tt = t + k - 1;
    if (tt < 0 || tt >= LL) continue;
    const float* xr = x + (b * LL + tt) * 9;
    const float* wr = w + i * 27 + k;
#pragma unroll
    for (int c = 0; c < 9; ++c) acc += xr[c] * wr[c * 3];
  }
  f1[idx] = fmaxf(acc, 0.f);
}

// ------- conv2: f1 (B,L,128) -> featH/featL (B,L,256) bf16 split, relu -------
__global__ __launch_bounds__(256) void k2_conv2(const float* __restrict__ f1,
    const float* __restrict__ w, const float* __restrict__ bias,
    u16* __restrict__ featH, u16* __restrict__ featL) {
  __shared__ float f1s[18][128];
  int blk = blockIdx.x;
  int b = blk >> 7;
  int t0 = (blk & 127) * 16;
  int o = threadIdx.x;
  for (int i = threadIdx.x; i < 18 * 128; i += 256) {
    int c = i & 127;
    int r = i >> 7;
    int tt = t0 - 1 + r;
    f1s[r][c] = (tt >= 0 && tt < LL) ? f1[(b * LL + tt) * 128 + c] : 0.f;
  }
  __syncthreads();
  float acc[16];
#pragma unroll
  for (int tt = 0; tt < 16; ++tt) acc[tt] = bias[o];
  const float* wr = w + o * 384;
  for (int i = 0; i < 128; ++i) {
    float w0 = wr[i * 3 + 0];
    float w1 = wr[i * 3 + 1];
    float w2 = wr[i * 3 + 2];
#pragma unroll
    for (int tt = 0; tt < 16; ++tt)
      acc[tt] += f1s[tt][i] * w0 + f1s[tt + 1][i] * w1 + f1s[tt + 2][i] * w2;
  }
#pragma unroll
  for (int tt = 0; tt < 16; ++tt) {
    float v = fmaxf(acc[tt], 0.f);
    int idx = (b * LL + t0 + tt) * 256 + o;
    u16 h = f2b(v);
    featH[idx] = h;
    featL[idx] = f2b(v - b2f(h));
  }
}

// ---------------- weight split fp32 -> bf16 H/L ----------------
__global__ __launch_bounds__(256) void k_wsplit(const float* __restrict__ w,
    u16* __restrict__ H, u16* __restrict__ L, int n) {
  int i = blockIdx.x * 256 + threadIdx.x;
  if (i >= n) return;
  float v = w[i];
  u16 h = f2b(v);
  H[i] = h;
  L[i] = f2b(v - b2f(h));
}

// ------- MFMA GEMM: C[M,N] = A[M,K] @ W[N,K]^T, bf16x2-split operands -------
// grid (N/128, M/128), 256 thr = 4 waves (2x2), wave tile 64x64.
// Direct-global fragment loads (no LDS). 16x16x32 bf16 MFMA, 3-product split.
__global__ __launch_bounds__(256) void k_gemm_mfma(
    const u16* __restrict__ AH, const u16* __restrict__ AL,
    const u16* __restrict__ BH, const u16* __restrict__ BL,
    float* __restrict__ C, int N, int K) {
  int bn = blockIdx.x, bm = blockIdx.y;
  int wid = threadIdx.x >> 6;
  int lane = threadIdx.x & 63;
  int wr = wid >> 1, wc = wid & 1;
  int m0 = bm * 128 + wr * 64;
  int n0 = bn * 128 + wc * 64;
  int lrow = lane & 15;
  int lk = (lane >> 4) << 3;            // 0,8,16,24
  f32x4 acc[4][4] = {};
  const u16* pAH = AH + (size_t)(m0 + lrow) * K + lk;
  const u16* pAL = AL + (size_t)(m0 + lrow) * K + lk;
  const u16* pBH = BH + (size_t)(n0 + lrow) * K + lk;
  const u16* pBL = BL + (size_t)(n0 + lrow) * K + lk;
  for (int k0 = 0; k0 < K; k0 += 32) {
    bf16x8 aH[4], aL[4], bH[4], bL[4];
#pragma unroll
    for (int t = 0; t < 4; ++t) {
      size_t off = (size_t)(t * 16) * K + k0;
      aH[t] = *(const bf16x8*)(pAH + off);
      aL[t] = *(const bf16x8*)(pAL + off);
      bH[t] = *(const bf16x8*)(pBH + off);
      bL[t] = *(const bf16x8*)(pBL + off);
    }
#pragma unroll
    for (int i = 0; i < 4; ++i)
#pragma unroll
      for (int j = 0; j < 4; ++j) {
        acc[i][j] = __builtin_amdgcn_mfma_f32_16x16x32_bf16(aH[i], bH[j], acc[i][j], 0, 0, 0);
        acc[i][j] = __builtin_amdgcn_mfma_f32_16x16x32_bf16(aH[i], bL[j], acc[i][j], 0, 0, 0);
        acc[i][j] = __builtin_amdgcn_mfma_f32_16x16x32_bf16(aL[i], bH[j], acc[i][j], 0, 0, 0);
      }
  }
  int orow = (lane >> 4) << 2;
#pragma unroll
  for (int i = 0; i < 4; ++i)
#pragma unroll
    for (int j = 0; j < 4; ++j)
#pragma unroll
      for (int r = 0; r < 4; ++r)
        C[(size_t)(m0 + i * 16 + orow + r) * N + n0 + j * 16 + lrow] = acc[i][j][r];
}

// ---------------- depthwise causal conv4 + silu: xz -> u (B,L,512) ----------------
__global__ __launch_bounds__(256) void k4_dwconv(const float* __restrict__ xz,
    const float* __restrict__ w, const float* __restrict__ bias,
    float* __restrict__ u) {
  int idx = blockIdx.x * 256 + threadIdx.x;
  int d = idx & 511;
  int t = (idx >> 9) & (LL - 1);
  int b = idx >> 20;
  float acc = bias[d];
#pragma unroll
  for (int k = 0; k < 4; ++k) {
    int tt = t - 3 + k;
    if (tt >= 0) acc += xz[(b * LL + tt) * 1024 + d] * w[d * 4 + k];
  }
  float sig = 1.f / (1.f + __expf(-acc));
  u[idx] = acc * sig;
}

// ---------------- x_proj (LDS-staged): u (8192,512) @ w(48,512)^T -> xdbl ----
__global__ __launch_bounds__(256) void k5_xproj(const float* __restrict__ u,
    const float* __restrict__ w, float* __restrict__ xdbl) {
  __shared__ float As[32][129];
  __shared__ float Ws[48][129];
  int r0 = blockIdx.x * 32;
  int tid = threadIdx.x;
  int r = tid >> 3;
  int jg = tid & 7;
  float acc[6] = {};
  for (int k0 = 0; k0 < 512; k0 += 128) {
    __syncthreads();
    for (int i = tid; i < 32 * 32; i += 256) {
      int rr = i >> 5;
      int cc = (i & 31) << 2;
      float4 v = *(const float4*)(u + (size_t)(r0 + rr) * 512 + k0 + cc);
      As[rr][cc] = v.x; As[rr][cc + 1] = v.y; As[rr][cc + 2] = v.z; As[rr][cc + 3] = v.w;
    }
    for (int i = tid; i < 48 * 32; i += 256) {
      int jj = i >> 5;
      int cc = (i & 31) << 2;
      float4 v = *(const float4*)(w + (size_t)jj * 512 + k0 + cc);
      Ws[jj][cc] = v.x; Ws[jj][cc + 1] = v.y; Ws[jj][cc + 2] = v.z; Ws[jj][cc + 3] = v.w;
    }
    __syncthreads();
    for (int k = 0; k < 128; ++k) {
      float a = As[r][k];
#pragma unroll
      for (int jj = 0; jj < 6; ++jj)
        acc[jj] += a * Ws[jg * 6 + jj][k];
    }
  }
  int row = r0 + r;
#pragma unroll
  for (int jj = 0; jj < 6; ++jj)
    xdbl[(size_t)row * 48 + jg * 6 + jj] = acc[jj];
}

// ---------------- dt: softplus(dt_lr @ dt_proj_w^T + b) -> (8192,512) ----------------
__global__ __launch_bounds__(256) void k6_dt(const float* __restrict__ xdbl,
    const float* __restrict__ w, const float* __restrict__ bias,
    float* __restrict__ dt) {
  int idx = blockIdx.x * 256 + threadIdx.x;
  int d = idx & 511;
  int row = idx >> 9;
  const float* lr = xdbl + row * 48;
  const float* wr = w + d * 16;
  float acc = bias[d];
#pragma unroll
  for (int r = 0; r < 16; ++r) acc += lr[r] * wr[r];
  dt[idx] = (acc > 20.f) ? acc : log1pf(expf(acc));
}

// ======== chunked selective scan: 3 passes ========
__global__ __launch_bounds__(512) void k7a_pass1(const float* __restrict__ dt,
    const float* __restrict__ u, const float* __restrict__ xdbl,
    const float* __restrict__ A_log, float* __restrict__ hloc,
    float* __restrict__ dtsum) {
  __shared__ float Bs[CH][16];
  int b = blockIdx.x >> 6;
  int c = blockIdx.x & (NC - 1);
  int d = threadIdx.x;
  {
    int t = threadIdx.x >> 4, s = threadIdx.x & 15;
    Bs[t][s] = xdbl[(b * LL + c * CH + t) * 48 + 16 + s];
  }
  __syncthreads();
  float A_r[16];
#pragma unroll
  for (int s = 0; s < 16; ++s) A_r[s] = -__expf(A_log[d * 16 + s]);
  float h[16];
#pragma unroll
  for (int s = 0; s < 16; ++s) h[s] = 0.f;
  float dsum = 0.f;
  const float* dtp = dt + (size_t)(b * LL + c * CH) * 512 + d;
  const float* up  = u  + (size_t)(b * LL + c * CH) * 512 + d;
  for (int t = 0; t < CH; ++t) {
    float dtv = dtp[t * 512];
    float uv  = up[t * 512];
    float xv = dtv * uv;
    dsum += dtv;
#pragma unroll
    for (int s = 0; s < 16; ++s)
      h[s] = h[s] * __expf(dtv * A_r[s]) + xv * Bs[t][s];
  }
  int base = b * NC + c;
#pragma unroll
  for (int s = 0; s < 16; ++s) hloc[(base * 16 + s) * 512 + d] = h[s];
  dtsum[base * 512 + d] = dsum;
}

__global__ __launch_bounds__(512) void k7b_combine(const float* __restrict__ hloc,
    const float* __restrict__ dtsum, const float* __restrict__ A_log,
    float* __restrict__ h_in) {
  int g = blockIdx.x * 512 + threadIdx.x;
  int d = g & 511;
  int s = (g >> 9) & 15;
  int b = g >> 13;
  float A_r = -__expf(A_log[d * 16 + s]);
  float H = 0.f;
  for (int c = 0; c < NC; ++c) {
    int base = b * NC + c;
    h_in[(base * 16 + s) * 512 + d] = H;
    float P = __expf(A_r * dtsum[base * 512 + d]);
    H = P * H + hloc[(base * 16 + s) * 512 + d];
  }
}

// pass3: replay + gate; writes y2 as bf16 H/L split for the out_proj MFMA
__global__ __launch_bounds__(512) void k7c_pass3(const float* __restrict__ dt,
    const float* __restrict__ u, const float* __restrict__ xdbl,
    const float* __restrict__ xz, const float* __restrict__ A_log,
    const float* __restrict__ D_param, const float* __restrict__ h_in,
    u16* __restrict__ y2H, u16* __restrict__ y2L) {
  __shared__ float BC[CH][32];
  int b = blockIdx.x >> 6;
  int c = blockIdx.x & (NC - 1);
  int d = threadIdx.x;
  for (int i = threadIdx.x; i < CH * 32; i += 512) {
    int t = i >> 5, j = i & 31;
    BC[t][j] = xdbl[(b * LL + c * CH + t) * 48 + 16 + j];
  }
  __syncthreads();
  float A_r[16];
#pragma unroll
  for (int s = 0; s < 16; ++s) A_r[s] = -__expf(A_log[d * 16 + s]);
  float Dv = D_param[d];
  int base = b * NC + c;
  float h[16];
#pragma unroll
  for (int s = 0; s < 16; ++s) h[s] = h_in[(base * 16 + s) * 512 + d];
  for (int t = 0; t < CH; ++t) {
    int row = b * LL + c * CH + t;
    float dtv = dt[(size_t)row * 512 + d];
    float uv  = u[(size_t)row * 512 + d];
    float xv = dtv * uv;
    float y = 0.f;
#pragma unroll
    for (int s = 0; s < 16; ++s) {
      h[s] = h[s] * __expf(dtv * A_r[s]) + xv * BC[t][s];
      y += h[s] * BC[t][16 + s];
    }
    float zv = xz[(size_t)row * 1024 + 512 + d];
    float sig = 1.f / (1.f + __expf(-zv));
    float v = (y + Dv * uv) * (zv * sig);
    u16 hh = f2b(v);
    y2H[(size_t)row * 512 + d] = hh;
    y2L[(size_t)row * 512 + d] = f2b(v - b2f(hh));
  }
}

// ---------------- partial max over t-chunks: mo (B,L,256) -> part (B*32,256) ----------------
__global__ __launch_bounds__(256) void k9_pmax(const float* __restrict__ mo,
    float* __restrict__ part) {
  int blk = blockIdx.x;
  int b = blk >> 5;
  int ch = blk & 31;
  int o = threadIdx.x;
  float m = -FLT_MAX;
  for (int tt = 0; tt < 64; ++tt)
    m = fmaxf(m, mo[(b * LL + ch * 64 + tt) * 256 + o]);
  part[blk * 256 + o] = m;
}

// ---------------- final: max-reduce + fc1 relu + fc2 -> out (4,4) ----------------
__global__ __launch_bounds__(256) void k10_head(const float* __restrict__ part,
    const float* __restrict__ fc1_w, const float* __restrict__ fc1_b,
    const float* __restrict__ fc2_w, const float* __restrict__ fc2_b,
    float* __restrict__ out) {
  __shared__ float pooled[4][256];
  __shared__ float hbuf[4][128];
  int tid = threadIdx.x;
  for (int idx = tid; idx < 1024; idx += 256) {
    int b = idx >> 8, o = idx & 255;
    float m = -FLT_MAX;
    for (int c = 0; c < 32; ++c) m = fmaxf(m, part[(b * 32 + c) * 256 + o]);
    pooled[b][o] = m;
  }
  __syncthreads();
  for (int idx = tid; idx < 512; idx += 256) {
    int b = idx >> 7, i = idx & 127;
    float acc = fc1_b[i];
    for (int o = 0; o < 256; ++o) acc += pooled[b][o] * fc1_w[i * 256 + o];
    hbuf[b][i] = fmaxf(acc, 0.f);
  }
  __syncthreads();
  if (tid < 16) {
    int b = tid >> 2, c = tid & 3;
    float acc = fc2_b[c];
    for (int i = 0; i < 128; ++i) acc += hbuf[b][i] * fc2_w[c * 128 + i];
    out[b * 4 + c] = acc;
  }
}

extern "C" void kernel_launch(void* const* d_in, const int* in_sizes, int n_in,
                              void* d_out, int out_size, void* d_ws, size_t ws_size,
                              hipStream_t stream) {
  (void)in_sizes; (void)n_in; (void)out_size; (void)ws_size;
  const float* x        = (const float*)d_in[0];
  const float* conv1_w  = (const float*)d_in[1];
  const float* conv1_b  = (const float*)d_in[2];
  const float* conv2_w  = (const float*)d_in[3];
  const float* conv2_b  = (const float*)d_in[4];
  const float* in_proj_w= (const float*)d_in[5];
  const float* dw_w     = (const float*)d_in[6];
  const float* dw_b     = (const float*)d_in[7];
  const float* x_proj_w = (const float*)d_in[8];
  const float* dt_proj_w= (const float*)d_in[9];
  const float* dt_proj_b= (const float*)d_in[10];
  const float* A_log    = (const float*)d_in[11];
  const float* D_param  = (const float*)d_in[12];
  const float* out_proj_w=(const float*)d_in[13];
  const float* fc1_w    = (const float*)d_in[14];
  const float* fc1_b    = (const float*)d_in[15];
  const float* fc2_w    = (const float*)d_in[16];
  const float* fc2_b    = (const float*)d_in[17];
  float* out = (float*)d_out;

  float* ws = (float*)d_ws;
  float* f1   = ws;                    // 1048576 floats
  float* feat = f1 + 1048576;          // 2097152 (now holds featH/featL bf16)
  float* xz   = feat + 2097152;        // 8388608
  float* u    = xz + 8388608;          // 4194304 (holds wH/wL before k4 writes)
  float* xdbl = u + 4194304;           // 393216
  float* dt   = xdbl + 393216;         // 4194304
  float* y2   = dt + 4194304;          // 4194304 (holds y2H/y2L bf16)
  float* mo   = y2 + 4194304;          // 2097152
  float* part = mo + 2097152;          // 32768

  // aliases onto dead regions
  float* hloc  = mo;                   // free until out_proj
  float* h_in  = feat;                 // free after in_proj consumed featH/L
  float* dtsum = f1;                   // f1[0:131072), free after conv2

  u16* featH = (u16*)feat;
  u16* featL = (u16*)(feat + 1048576);
  u16* wH    = (u16*)u;                // 262144 elems = 131072 floats
  u16* wL    = (u16*)(u + 131072);
  u16* owH   = (u16*)(f1 + 262144);    // 131072 elems = 65536 floats
  u16* owL   = (u16*)(f1 + 327680);
  u16* y2H   = (u16*)y2;
  u16* y2L   = (u16*)(y2 + 2097152);

  k1_conv1<<<dim3(BB * LL * 128 / 256), dim3(256), 0, stream>>>(x, conv1_w, conv1_b, f1);
  k2_conv2<<<dim3(BB * 128), dim3(256), 0, stream>>>(f1, conv2_w, conv2_b, featH, featL);
  k_wsplit<<<dim3(262144 / 256), dim3(256), 0, stream>>>(in_proj_w, wH, wL, 262144);
  k_wsplit<<<dim3(131072 / 256), dim3(256), 0, stream>>>(out_proj_w, owH, owL, 131072);
  // in_proj: (8192,256) @ (1024,256)^T -> xz
  k_gemm_mfma<<<dim3(1024 / 128, 8192 / 128), dim3(256), 0, stream>>>(featH, featL, wH, wL, xz, 1024, 256);
  k4_dwconv<<<dim3(BB * LL * 512 / 256), dim3(256), 0, stream>>>(xz, dw_w, dw_b, u);
  k5_xproj<<<dim3(256), dim3(256), 0, stream>>>(u, x_proj_w, xdbl);
  k6_dt<<<dim3(BB * LL * 512 / 256), dim3(256), 0, stream>>>(xdbl, dt_proj_w, dt_proj_b, dt);
  k7a_pass1<<<dim3(BB * NC), dim3(512), 0, stream>>>(dt, u, xdbl, A_log, hloc, dtsum);
  k7b_combine<<<dim3(BB * 16), dim3(512), 0, stream>>>(hloc, dtsum, A_log, h_in);
  k7c_pass3<<<dim3(BB * NC), dim3(512), 0, stream>>>(dt, u, xdbl, xz, A_log, D_param, h_in, y2H, y2L);
  // out_proj: (8192,512) @ (256,512)^T -> mo
  k_gemm_mfma<<<dim3(256 / 128, 8192 / 128), dim3(256), 0, stream>>>(y2H, y2L, owH, owL, mo, 256, 512);
  k9_pmax<<<dim3(128), dim3(256), 0, stream>>>(mo, part);
  k10_head<<<dim3(1), dim3(256), 0, stream>>>(part, fc1_w, fc1_b, fc2_w, fc2_b, out);
}

// Round 5
// 317.260 us; speedup vs baseline: 5.5911x; 1.0543x over previous
//
#include <hip/hip_runtime.h>
#include <cfloat>

#define BB 4
#define LL 2048
#define DMODEL 256
#define DINNER 512
#define DSTATE 16
#define DTRANK 16
#define HID 128
#define NCLS 4
#define CH 32
#define NC 64

typedef unsigned short u16;
typedef __attribute__((ext_vector_type(8))) short bf16x8;
typedef __attribute__((ext_vector_type(4))) float f32x4;

__device__ inline u16 f2b(float v) {
  union { float f; unsigned u; } c; c.f = v;
  unsigned r = c.u + 0x7fffu + ((c.u >> 16) & 1u);
  return (u16)(r >> 16);
}
__device__ inline float b2f(u16 h) {
  union { unsigned u; float f; } c; c.u = ((unsigned)h) << 16;
  return c.f;
}

// ------- conv1: x (B,L,9) -> f1H/f1L (B,L,128) bf16 split, relu -------
__global__ __launch_bounds__(256) void k1_conv1(const float* __restrict__ x,
    const float* __restrict__ w, const float* __restrict__ bias,
    u16* __restrict__ f1H, u16* __restrict__ f1L) {
  int idx = blockIdx.x * 256 + threadIdx.x;
  int i = idx & 127;
  int t = (idx >> 7) & (LL - 1);
  int b = idx >> 18;
  float acc = bias[i];
#pragma unroll
  for (int k = 0; k < 3; ++k) {
    int tt = t + k - 1;
    if (tt < 0 || tt >= LL) continue;
    const float* xr = x + (b * LL + tt) * 9;
    const float* wr = w + i * 27 + k;
#pragma unroll
    for (int c = 0; c < 9; ++c) acc += xr[c] * wr[c * 3];
  }
  float v = fmaxf(acc, 0.f);
  u16 h = f2b(v);
  f1H[idx] = h;
  f1L[idx] = f2b(v - b2f(h));
}

// ------- conv2 weight reorder: w (256,128,3) -> W'[o][tap*128+i] H/L -------
__global__ __launch_bounds__(256) void k_wconv2(const float* __restrict__ w,
    u16* __restrict__ H, u16* __restrict__ L) {
  int idx = blockIdx.x * 256 + threadIdx.x;   // o*384 + tap*128 + i
  if (idx >= 256 * 384) return;
  int o = idx / 384;
  int r = idx - o * 384;
  int tap = r >> 7;
  int i = r & 127;
  float v = w[o * 384 + i * 3 + tap];
  u16 h = f2b(v);
  H[idx] = h;
  L[idx] = f2b(v - b2f(h));
}

// ------- conv2 as MFMA GEMM: K=384 (3 shifted taps of f1), bias+relu+split ----
// grid (2, 64): 128x128 tiles over (8192, 256). 4 waves, wave 64x64.
__global__ __launch_bounds__(256) void k2_conv2_mfma(
    const u16* __restrict__ f1H, const u16* __restrict__ f1L,
    const u16* __restrict__ WH, const u16* __restrict__ WL,
    const float* __restrict__ bias,
    u16* __restrict__ featH, u16* __restrict__ featL) {
  int bn = blockIdx.x, bm = blockIdx.y;
  int wid = threadIdx.x >> 6;
  int lane = threadIdx.x & 63;
  int wr = wid >> 1, wc = wid & 1;
  int m0 = bm * 128 + wr * 64;
  int n0 = bn * 128 + wc * 64;
  int lrow = lane & 15;
  int lk8 = (lane >> 4) << 3;
  const bf16x8 zv = {};
  f32x4 acc[4][4] = {};
  for (int kk = 0; kk < 12; ++kk) {
    int tap = kk >> 2;
    int i0 = (kk & 3) * 32 + lk8;
    bf16x8 aH[4], aL[4], bH[4], bL[4];
#pragma unroll
    for (int i = 0; i < 4; ++i) {
      int row = m0 + i * 16 + lrow;
      int t = row & (LL - 1);
      int tt = t + tap - 1;
      bool valid = (tt >= 0) && (tt < LL);
      size_t off = (size_t)(row + tap - 1) * 128 + i0;
      aH[i] = valid ? *(const bf16x8*)(f1H + off) : zv;
      aL[i] = valid ? *(const bf16x8*)(f1L + off) : zv;
    }
#pragma unroll
    for (int j = 0; j < 4; ++j) {
      size_t off = (size_t)(n0 + j * 16 + lrow) * 384 + kk * 32 + lk8;
      bH[j] = *(const bf16x8*)(WH + off);
      bL[j] = *(const bf16x8*)(WL + off);
    }
#pragma unroll
    for (int i = 0; i < 4; ++i)
#pragma unroll
      for (int j = 0; j < 4; ++j) {
        acc[i][j] = __builtin_amdgcn_mfma_f32_16x16x32_bf16(aH[i], bH[j], acc[i][j], 0, 0, 0);
        acc[i][j] = __builtin_amdgcn_mfma_f32_16x16x32_bf16(aH[i], bL[j], acc[i][j], 0, 0, 0);
        acc[i][j] = __builtin_amdgcn_mfma_f32_16x16x32_bf16(aL[i], bH[j], acc[i][j], 0, 0, 0);
      }
  }
  int orow = (lane >> 4) << 2;
#pragma unroll
  for (int i = 0; i < 4; ++i)
#pragma unroll
    for (int j = 0; j < 4; ++j)
#pragma unroll
      for (int r = 0; r < 4; ++r) {
        int row = m0 + i * 16 + orow + r;
        int o = n0 + j * 16 + lrow;
        float v = fmaxf(acc[i][j][r] + bias[o], 0.f);
        u16 h = f2b(v);
        featH[(size_t)row * 256 + o] = h;
        featL[(size_t)row * 256 + o] = f2b(v - b2f(h));
      }
}

// ---------------- weight split fp32 -> bf16 H/L ----------------
__global__ __launch_bounds__(256) void k_wsplit(const float* __restrict__ w,
    u16* __restrict__ H, u16* __restrict__ L, int n) {
  int i = blockIdx.x * 256 + threadIdx.x;
  if (i >= n) return;
  float v = w[i];
  u16 h = f2b(v);
  H[i] = h;
  L[i] = f2b(v - b2f(h));
}

// ------- MFMA GEMM: C[M,N] = A[M,K] @ W[N,K]^T, bf16x2-split operands -------
__global__ __launch_bounds__(256) void k_gemm_mfma(
    const u16* __restrict__ AH, const u16* __restrict__ AL,
    const u16* __restrict__ BH, const u16* __restrict__ BL,
    float* __restrict__ C, int N, int K) {
  int bn = blockIdx.x, bm = blockIdx.y;
  int wid = threadIdx.x >> 6;
  int lane = threadIdx.x & 63;
  int wr = wid >> 1, wc = wid & 1;
  int m0 = bm * 128 + wr * 64;
  int n0 = bn * 128 + wc * 64;
  int lrow = lane & 15;
  int lk = (lane >> 4) << 3;
  f32x4 acc[4][4] = {};
  const u16* pAH = AH + (size_t)(m0 + lrow) * K + lk;
  const u16* pAL = AL + (size_t)(m0 + lrow) * K + lk;
  const u16* pBH = BH + (size_t)(n0 + lrow) * K + lk;
  const u16* pBL = BL + (size_t)(n0 + lrow) * K + lk;
  for (int k0 = 0; k0 < K; k0 += 32) {
    bf16x8 aH[4], aL[4], bH[4], bL[4];
#pragma unroll
    for (int t = 0; t < 4; ++t) {
      size_t off = (size_t)(t * 16) * K + k0;
      aH[t] = *(const bf16x8*)(pAH + off);
      aL[t] = *(const bf16x8*)(pAL + off);
      bH[t] = *(const bf16x8*)(pBH + off);
      bL[t] = *(const bf16x8*)(pBL + off);
    }
#pragma unroll
    for (int i = 0; i < 4; ++i)
#pragma unroll
      for (int j = 0; j < 4; ++j) {
        acc[i][j] = __builtin_amdgcn_mfma_f32_16x16x32_bf16(aH[i], bH[j], acc[i][j], 0, 0, 0);
        acc[i][j] = __builtin_amdgcn_mfma_f32_16x16x32_bf16(aH[i], bL[j], acc[i][j], 0, 0, 0);
        acc[i][j] = __builtin_amdgcn_mfma_f32_16x16x32_bf16(aL[i], bH[j], acc[i][j], 0, 0, 0);
      }
  }
  int orow = (lane >> 4) << 2;
#pragma unroll
  for (int i = 0; i < 4; ++i)
#pragma unroll
    for (int j = 0; j < 4; ++j)
#pragma unroll
      for (int r = 0; r < 4; ++r)
        C[(size_t)(m0 + i * 16 + orow + r) * N + n0 + j * 16 + lrow] = acc[i][j][r];
}

// ---------------- depthwise causal conv4 + silu: xz -> u (B,L,512) ----------------
__global__ __launch_bounds__(256) void k4_dwconv(const float* __restrict__ xz,
    const float* __restrict__ w, const float* __restrict__ bias,
    float* __restrict__ u) {
  int idx = blockIdx.x * 256 + threadIdx.x;
  int d = idx & 511;
  int t = (idx >> 9) & (LL - 1);
  int b = idx >> 20;
  float acc = bias[d];
#pragma unroll
  for (int k = 0; k < 4; ++k) {
    int tt = t - 3 + k;
    if (tt >= 0) acc += xz[(b * LL + tt) * 1024 + d] * w[d * 4 + k];
  }
  float sig = 1.f / (1.f + __expf(-acc));
  u[idx] = acc * sig;
}

// ---------------- x_proj (LDS-staged): u (8192,512) @ w(48,512)^T -> xdbl ----
__global__ __launch_bounds__(256) void k5_xproj(const float* __restrict__ u,
    const float* __restrict__ w, float* __restrict__ xdbl) {
  __shared__ float As[32][129];
  __shared__ float Ws[48][129];
  int r0 = blockIdx.x * 32;
  int tid = threadIdx.x;
  int r = tid >> 3;
  int jg = tid & 7;
  float acc[6] = {};
  for (int k0 = 0; k0 < 512; k0 += 128) {
    __syncthreads();
    for (int i = tid; i < 32 * 32; i += 256) {
      int rr = i >> 5;
      int cc = (i & 31) << 2;
      float4 v = *(const float4*)(u + (size_t)(r0 + rr) * 512 + k0 + cc);
      As[rr][cc] = v.x; As[rr][cc + 1] = v.y; As[rr][cc + 2] = v.z; As[rr][cc + 3] = v.w;
    }
    for (int i = tid; i < 48 * 32; i += 256) {
      int jj = i >> 5;
      int cc = (i & 31) << 2;
      float4 v = *(const float4*)(w + (size_t)jj * 512 + k0 + cc);
      Ws[jj][cc] = v.x; Ws[jj][cc + 1] = v.y; Ws[jj][cc + 2] = v.z; Ws[jj][cc + 3] = v.w;
    }
    __syncthreads();
    for (int k = 0; k < 128; ++k) {
      float a = As[r][k];
#pragma unroll
      for (int jj = 0; jj < 6; ++jj)
        acc[jj] += a * Ws[jg * 6 + jj][k];
    }
  }
  int row = r0 + r;
#pragma unroll
  for (int jj = 0; jj < 6; ++jj)
    xdbl[(size_t)row * 48 + jg * 6 + jj] = acc[jj];
}

// ---------------- dt: softplus(dt_lr @ dt_proj_w^T + b) -> (8192,512) ----------------
__global__ __launch_bounds__(256) void k6_dt(const float* __restrict__ xdbl,
    const float* __restrict__ w, const float* __restrict__ bias,
    float* __restrict__ dt) {
  int idx = blockIdx.x * 256 + threadIdx.x;
  int d = idx & 511;
  int row = idx >> 9;
  const float* lr = xdbl + row * 48;
  const float* wr = w + d * 16;
  float acc = bias[d];
#pragma unroll
  for (int r = 0; r < 16; ++r) acc += lr[r] * wr[r];
  dt[idx] = (acc > 20.f) ? acc : log1pf(expf(acc));
}

// ======== chunked selective scan: 3 passes ========
__global__ __launch_bounds__(512) void k7a_pass1(const float* __restrict__ dt,
    const float* __restrict__ u, const float* __restrict__ xdbl,
    const float* __restrict__ A_log, float* __restrict__ hloc,
    float* __restrict__ dtsum) {
  __shared__ float Bs[CH][16];
  int b = blockIdx.x >> 6;
  int c = blockIdx.x & (NC - 1);
  int d = threadIdx.x;
  {
    int t = threadIdx.x >> 4, s = threadIdx.x & 15;
    Bs[t][s] = xdbl[(b * LL + c * CH + t) * 48 + 16 + s];
  }
  __syncthreads();
  float A_r[16];
#pragma unroll
  for (int s = 0; s < 16; ++s) A_r[s] = -__expf(A_log[d * 16 + s]);
  float h[16];
#pragma unroll
  for (int s = 0; s < 16; ++s) h[s] = 0.f;
  float dsum = 0.f;
  const float* dtp = dt + (size_t)(b * LL + c * CH) * 512 + d;
  const float* up  = u  + (size_t)(b * LL + c * CH) * 512 + d;
  for (int t = 0; t < CH; ++t) {
    float dtv = dtp[t * 512];
    float uv  = up[t * 512];
    float xv = dtv * uv;
    dsum += dtv;
#pragma unroll
    for (int s = 0; s < 16; ++s)
      h[s] = h[s] * __expf(dtv * A_r[s]) + xv * Bs[t][s];
  }
  int base = b * NC + c;
#pragma unroll
  for (int s = 0; s < 16; ++s) hloc[(base * 16 + s) * 512 + d] = h[s];
  dtsum[base * 512 + d] = dsum;
}

__global__ __launch_bounds__(512) void k7b_combine(const float* __restrict__ hloc,
    const float* __restrict__ dtsum, const float* __restrict__ A_log,
    float* __restrict__ h_in) {
  int g = blockIdx.x * 512 + threadIdx.x;
  int d = g & 511;
  int s = (g >> 9) & 15;
  int b = g >> 13;
  float A_r = -__expf(A_log[d * 16 + s]);
  float H = 0.f;
  for (int c = 0; c < NC; ++c) {
    int base = b * NC + c;
    h_in[(base * 16 + s) * 512 + d] = H;
    float P = __expf(A_r * dtsum[base * 512 + d]);
    H = P * H + hloc[(base * 16 + s) * 512 + d];
  }
}

__global__ __launch_bounds__(512) void k7c_pass3(const float* __restrict__ dt,
    const float* __restrict__ u, const float* __restrict__ xdbl,
    const float* __restrict__ xz, const float* __restrict__ A_log,
    const float* __restrict__ D_param, const float* __restrict__ h_in,
    u16* __restrict__ y2H, u16* __restrict__ y2L) {
  __shared__ float BC[CH][32];
  int b = blockIdx.x >> 6;
  int c = blockIdx.x & (NC - 1);
  int d = threadIdx.x;
  for (int i = threadIdx.x; i < CH * 32; i += 512) {
    int t = i >> 5, j = i & 31;
    BC[t][j] = xdbl[(b * LL + c * CH + t) * 48 + 16 + j];
  }
  __syncthreads();
  float A_r[16];
#pragma unroll
  for (int s = 0; s < 16; ++s) A_r[s] = -__expf(A_log[d * 16 + s]);
  float Dv = D_param[d];
  int base = b * NC + c;
  float h[16];
#pragma unroll
  for (int s = 0; s < 16; ++s) h[s] = h_in[(base * 16 + s) * 512 + d];
  for (int t = 0; t < CH; ++t) {
    int row = b * LL + c * CH + t;
    float dtv = dt[(size_t)row * 512 + d];
    float uv  = u[(size_t)row * 512 + d];
    float xv = dtv * uv;
    float y = 0.f;
#pragma unroll
    for (int s = 0; s < 16; ++s) {
      h[s] = h[s] * __expf(dtv * A_r[s]) + xv * BC[t][s];
      y += h[s] * BC[t][16 + s];
    }
    float zv = xz[(size_t)row * 1024 + 512 + d];
    float sig = 1.f / (1.f + __expf(-zv));
    float v = (y + Dv * uv) * (zv * sig);
    u16 hh = f2b(v);
    y2H[(size_t)row * 512 + d] = hh;
    y2L[(size_t)row * 512 + d] = f2b(v - b2f(hh));
  }
}

// ---------------- partial max over t-chunks: mo (B,L,256) -> part (B*32,256) ----------------
__global__ __launch_bounds__(256) void k9_pmax(const float* __restrict__ mo,
    float* __restrict__ part) {
  int blk = blockIdx.x;
  int b = blk >> 5;
  int ch = blk & 31;
  int o = threadIdx.x;
  float m = -FLT_MAX;
  for (int tt = 0; tt < 64; ++tt)
    m = fmaxf(m, mo[(b * LL + ch * 64 + tt) * 256 + o]);
  part[blk * 256 + o] = m;
}

// ---------------- final: max-reduce + fc1 relu + fc2 -> out (4,4) ----------------
__global__ __launch_bounds__(256) void k10_head(const float* __restrict__ part,
    const float* __restrict__ fc1_w, const float* __restrict__ fc1_b,
    const float* __restrict__ fc2_w, const float* __restrict__ fc2_b,
    float* __restrict__ out) {
  __shared__ float pooled[4][256];
  __shared__ float hbuf[4][128];
  int tid = threadIdx.x;
  for (int idx = tid; idx < 1024; idx += 256) {
    int b = idx >> 8, o = idx & 255;
    float m = -FLT_MAX;
    for (int c = 0; c < 32; ++c) m = fmaxf(m, part[(b * 32 + c) * 256 + o]);
    pooled[b][o] = m;
  }
  __syncthreads();
  for (int idx = tid; idx < 512; idx += 256) {
    int b = idx >> 7, i = idx & 127;
    float acc = fc1_b[i];
    for (int o = 0; o < 256; ++o) acc += pooled[b][o] * fc1_w[i * 256 + o];
    hbuf[b][i] = fmaxf(acc, 0.f);
  }
  __syncthreads();
  if (tid < 16) {
    int b = tid >> 2, c = tid & 3;
    float acc = fc2_b[c];
    for (int i = 0; i < 128; ++i) acc += hbuf[b][i] * fc2_w[c * 128 + i];
    out[b * 4 + c] = acc;
  }
}

extern "C" void kernel_launch(void* const* d_in, const int* in_sizes, int n_in,
                              void* d_out, int out_size, void* d_ws, size_t ws_size,
                              hipStream_t stream) {
  (void)in_sizes; (void)n_in; (void)out_size; (void)ws_size;
  const float* x        = (const float*)d_in[0];
  const float* conv1_w  = (const float*)d_in[1];
  const float* conv1_b  = (const float*)d_in[2];
  const float* conv2_w  = (const float*)d_in[3];
  const float* conv2_b  = (const float*)d_in[4];
  const float* in_proj_w= (const float*)d_in[5];
  const float* dw_w     = (const float*)d_in[6];
  const float* dw_b     = (const float*)d_in[7];
  const float* x_proj_w = (const float*)d_in[8];
  const float* dt_proj_w= (const float*)d_in[9];
  const float* dt_proj_b= (const float*)d_in[10];
  const float* A_log    = (const float*)d_in[11];
  const float* D_param  = (const float*)d_in[12];
  const float* out_proj_w=(const float*)d_in[13];
  const float* fc1_w    = (const float*)d_in[14];
  const float* fc1_b    = (const float*)d_in[15];
  const float* fc2_w    = (const float*)d_in[16];
  const float* fc2_b    = (const float*)d_in[17];
  float* out = (float*)d_out;

  float* ws = (float*)d_ws;
  float* f1   = ws;                    // 1048576 floats: f1H/f1L bf16 (exact)
  float* feat = f1 + 1048576;          // 2097152: featH/featL bf16, later h_in
  float* xz   = feat + 2097152;        // 8388608
  float* u    = xz + 8388608;          // 4194304 (in_proj wH/wL before k4)
  float* xdbl = u + 4194304;           // 393216
  float* dt   = xdbl + 393216;         // 4194304
  float* y2   = dt + 4194304;          // 4194304: y2H/y2L bf16
  float* mo   = y2 + 4194304;          // 2097152 (conv2 W' early, hloc mid)
  float* part = mo + 2097152;          // 32768

  float* hloc  = mo;                   // k7a write -> k7b read; dead before out_proj
  float* h_in  = feat;                 // feat dead after in_proj
  float* dtsum = f1;                   // f1 dead after conv2... but owH/owL also here:
                                       //   dtsum uses f1[0:131072) and ow uses f1[262144:...)
  u16* f1H   = (u16*)f1;               // 1048576 elems
  u16* f1L   = f1H + 1048576;
  u16* featH = (u16*)feat;
  u16* featL = (u16*)(feat + 1048576);
  u16* wH    = (u16*)u;                // in_proj: 262144 elems each
  u16* wL    = wH + 262144;
  u16* wc2H  = (u16*)mo;               // conv2 W': 98304 elems each
  u16* wc2L  = wc2H + 98304;
  u16* owH   = (u16*)(f1 + 262144);    // out_proj: 131072 elems each (after conv2)
  u16* owL   = owH + 131072;
  u16* y2H   = (u16*)y2;
  u16* y2L   = (u16*)(y2 + 2097152);

  k1_conv1<<<dim3(BB * LL * 128 / 256), dim3(256), 0, stream>>>(x, conv1_w, conv1_b, f1H, f1L);
  k_wconv2<<<dim3((256 * 384 + 255) / 256), dim3(256), 0, stream>>>(conv2_w, wc2H, wc2L);
  k2_conv2_mfma<<<dim3(2, 64), dim3(256), 0, stream>>>(f1H, f1L, wc2H, wc2L, conv2_b, featH, featL);
  k_wsplit<<<dim3(262144 / 256), dim3(256), 0, stream>>>(in_proj_w, wH, wL, 262144);
  k_wsplit<<<dim3(131072 / 256), dim3(256), 0, stream>>>(out_proj_w, owH, owL, 131072);
  // in_proj: (8192,256) @ (1024,256)^T -> xz
  k_gemm_mfma<<<dim3(1024 / 128, 8192 / 128), dim3(256), 0, stream>>>(featH, featL, wH, wL, xz, 1024, 256);
  k4_dwconv<<<dim3(BB * LL * 512 / 256), dim3(256), 0, stream>>>(xz, dw_w, dw_b, u);
  k5_xproj<<<dim3(256), dim3(256), 0, stream>>>(u, x_proj_w, xdbl);
  k6_dt<<<dim3(BB * LL * 512 / 256), dim3(256), 0, stream>>>(xdbl, dt_proj_w, dt_proj_b, dt);
  k7a_pass1<<<dim3(BB * NC), dim3(512), 0, stream>>>(dt, u, xdbl, A_log, hloc, dtsum);
  k7b_combine<<<dim3(BB * 16), dim3(512), 0, stream>>>(hloc, dtsum, A_log, h_in);
  k7c_pass3<<<dim3(BB * NC), dim3(512), 0, stream>>>(dt, u, xdbl, xz, A_log, D_param, h_in, y2H, y2L);
  // out_proj: (8192,512) @ (256,512)^T -> mo
  k_gemm_mfma<<<dim3(256 / 128, 8192 / 128), dim3(256), 0, stream>>>(y2H, y2L, owH, owL, mo, 256, 512);
  k9_pmax<<<dim3(128), dim3(256), 0, stream>>>(mo, part);
  k10_head<<<dim3(1), dim3(256), 0, stream>>>(part, fc1_w, fc1_b, fc2_w, fc2_b, out);
}